// Round 2
// baseline (231.295 us; speedup 1.0000x reference)
//
#include <hip/hip_runtime.h>
#include <hip/hip_bf16.h>

// GATConv, N=8192, F_in=F_out=128, dense 0/1 adjacency (int32).
// Rank-1 logits: e_ij = LeakyReLU(es_i + ed_j), es = X@(W@a_src), ed = X@(W@a_dst).
// No max-shift needed (|logit| <~ 9 -> exp safe in f32); partial sums are additive.
//
// R2 changes vs R1 (latency-bound, 21.5% occupancy, vmcnt-serialized prefetch):
//  - k2: 16-row tiles, 512 blocks -> 16 waves/CU (VGPR<=128 keeps 4 waves/SIMD)
//  - k2 step order: [vb L2 loads][exp/pack][sched_barrier][A prefetch][MFMA] so the
//    MFMA vmcnt wait drains only vb, never the in-flight HBM A prefetch (in-order vmcnt)
//  - k0+k_esed fused into k1 (W LDS buffer aliased for wv/es/ed scratch)

typedef __bf16 bf16_t;
typedef bf16_t bf16x8 __attribute__((ext_vector_type(8)));
typedef float  f32x4  __attribute__((ext_vector_type(4)));
typedef int    i32x4  __attribute__((ext_vector_type(4)));

#define NN 8192
#define DD 128

// ---- K1: fused wv = W@a_{src,dst}; es/ed = X@wv; Hb = bf16(X@W) row-major ----
__global__ __launch_bounds__(256) void k1_fused(const float* __restrict__ X,
                                                const float* __restrict__ W,
                                                const float* __restrict__ a_src,
                                                const float* __restrict__ a_dst,
                                                float* __restrict__ es,
                                                float* __restrict__ ed,
                                                bf16_t* __restrict__ Hb) {
  __shared__ float Wl[DD * DD];  // 64 KB; [0..256) aliased as wsv/wdv, [256..320) es/ed scratch
  const int t = threadIdx.x;
  const int rb = blockIdx.x << 5;  // 32 rows per block

  // Phase 1: wsv (t<128) / wdv (t>=128), W rows from global (L2/L3-hot)
  {
    const int k = t & 127;
    const float* av = (t < 128) ? a_src : a_dst;
    const f32x4* wrow = (const f32x4*)(W + k * DD);
    float s = 0.f;
    #pragma unroll
    for (int c4 = 0; c4 < 32; ++c4) {
      const f32x4 wv = wrow[c4];
      const f32x4 avv = *(const f32x4*)(av + c4 * 4);
      s += wv[0] * avv[0] + wv[1] * avv[1] + wv[2] * avv[2] + wv[3] * avv[3];
    }
    Wl[t] = s;  // Wl[0..128)=wsv, Wl[128..256)=wdv
  }
  if (t < 64) Wl[256 + t] = 0.f;  // es/ed accumulators
  __syncthreads();

  // Phase 2: es[r] = X[r,:].wsv, ed[r] = X[r,:].wdv ; thread t: r=t>>3, c-chunk=(t&7)*16
  {
    const int r = t >> 3, part = t & 7;
    const f32x4* xrow = (const f32x4*)(X + (size_t)(rb + r) * DD + part * 16);
    float s = 0.f, d = 0.f;
    #pragma unroll
    for (int q = 0; q < 4; ++q) {
      const f32x4 xv = xrow[q];
      const f32x4 sv = *(const f32x4*)(Wl + part * 16 + q * 4);
      const f32x4 dv = *(const f32x4*)(Wl + 128 + part * 16 + q * 4);
      s += xv[0] * sv[0] + xv[1] * sv[1] + xv[2] * sv[2] + xv[3] * sv[3];
      d += xv[0] * dv[0] + xv[1] * dv[1] + xv[2] * dv[2] + xv[3] * dv[3];
    }
    atomicAdd(&Wl[256 + r], s);
    atomicAdd(&Wl[288 + r], d);
  }
  __syncthreads();
  if (t < 32) es[rb + t] = Wl[256 + t];
  else if (t < 64) ed[rb + t - 32] = Wl[288 + t - 32];
  __syncthreads();

  // Phase 3: stage full W into LDS (overwrites scratch)
  for (int idx = t; idx < DD * DD; idx += 256) Wl[idx] = W[idx];
  __syncthreads();

  // Phase 4: Hb = bf16(X@W), thread (c = t&127, r0 = t>>7)
  const int c = t & 127;
  const int r0 = t >> 7;
  for (int rr = 0; rr < 16; ++rr) {
    const int r = (rr << 1) + r0;
    const f32x4* xrow = (const f32x4*)(X + (size_t)(rb + r) * DD);
    float acc = 0.f;
    #pragma unroll
    for (int k4 = 0; k4 < 32; ++k4) {
      const f32x4 xv = xrow[k4];
      acc += xv[0] * Wl[(k4 * 4 + 0) * DD + c] + xv[1] * Wl[(k4 * 4 + 1) * DD + c] +
             xv[2] * Wl[(k4 * 4 + 2) * DD + c] + xv[3] * Wl[(k4 * 4 + 3) * DD + c];
    }
    Hb[(size_t)(rb + r) * DD + c] = (bf16_t)acc;
  }
}

// ---- K1T: HbT[c][j] = Hb[j][c]  (128 x 8192 bf16) ----
__global__ __launch_bounds__(256) void k1_transpose(const bf16_t* __restrict__ Hb,
                                                    bf16_t* __restrict__ HbT) {
  __shared__ bf16_t tile[64][72];  // padded
  const int jt = blockIdx.x << 6;
  const int ct = blockIdx.y << 6;
  const int t = threadIdx.x;
  for (int idx = t; idx < 4096; idx += 256) {
    const int r = idx >> 6, c = idx & 63;
    tile[r][c] = Hb[(size_t)(jt + r) * DD + ct + c];
  }
  __syncthreads();
  for (int idx = t; idx < 4096; idx += 256) {
    const int c = idx >> 6, r = idx & 63;
    HbT[(size_t)(ct + c) * NN + jt + r] = tile[r][c];
  }
}

// ---- K2: main. 512 WGs x 512 thr. WG owns 16 rows; 8 waves split the j axis. ----
__global__ __launch_bounds__(512) void k2_gat(const int* __restrict__ A,
                                              const float* __restrict__ es,
                                              const float* __restrict__ ed,
                                              const bf16_t* __restrict__ HbT,
                                              float* __restrict__ out) {
  __shared__ float numLDS[16 * DD];  // 8 KB
  __shared__ float denLDS[16];
  const int t = threadIdx.x;
  for (int idx = t; idx < 16 * DD; idx += 512) numLDS[idx] = 0.f;
  if (t < 16) denLDS[t] = 0.f;
  __syncthreads();

  const int wave = t >> 6;
  const int lane = t & 63;
  const int l16 = lane & 15;
  const int lk = lane >> 4;  // 0..3
  const int rowbase = blockIdx.x << 4;
  const int i0 = rowbase + l16;
  const float esv0 = es[i0];
  const int* Arow0 = A + (size_t)i0 * NN;

  f32x4 acc0[8];
  #pragma unroll
  for (int cf = 0; cf < 8; ++cf) acc0[cf] = f32x4{0.f, 0.f, 0.f, 0.f};
  float den0 = 0.f;

  auto ldA = [&](int s, i32x4& x00, i32x4& x01, f32x4& y0, f32x4& y1) {
    const int jj = (((s << 3) + wave) << 5) + (lk << 3);
    x00 = __builtin_nontemporal_load((const i32x4*)(Arow0 + jj));
    x01 = __builtin_nontemporal_load((const i32x4*)(Arow0 + jj + 4));
    y0 = *(const f32x4*)(ed + jj);
    y1 = *(const f32x4*)(ed + jj + 4);
  };

  auto step = [&](int s, i32x4& x00, i32x4& x01, f32x4& y0, f32x4& y1) {
    const int jj = (((s << 3) + wave) << 5) + (lk << 3);
    // (1) issue vb L2 loads FIRST (vmcnt is in-order: these must precede the A prefetch)
    bf16x8 vbr[8];
    const bf16_t* vbase = HbT + jj;
    #pragma unroll
    for (int cf = 0; cf < 8; ++cf)
      vbr[cf] = *(const bf16x8*)(vbase + (size_t)(cf * 16 + l16) * NN);
    // (2) exp/pack pa while vb is in flight (A(s) already arrived)
    bf16x8 pa0;
    float ps0 = 0.f;
    #pragma unroll
    for (int q = 0; q < 8; ++q) {
      const int av0 = (q < 4) ? x00[q] : x01[q - 4];
      const float edq = (q < 4) ? y0[q] : y1[q - 4];
      const int j = jj + q;
      float e0 = esv0 + edq;
      e0 = e0 > 0.f ? e0 : 0.2f * e0;
      const float p0 = (av0 > 0 || j == i0) ? __expf(e0) : 0.f;
      ps0 += p0;
      pa0[q] = (bf16_t)p0;
    }
    den0 += ps0;
    // (3) pin order: vb/exp stay above, A prefetch + MFMA stay below
    __builtin_amdgcn_sched_barrier(0);
    if (s + 2 < 32) ldA(s + 2, x00, x01, y0, y1);
    // (4) MFMAs: vmcnt wait drains vb (L2-latency, covered by (2)), A(s+2) stays in flight
    #pragma unroll
    for (int cf = 0; cf < 8; ++cf)
      acc0[cf] = __builtin_amdgcn_mfma_f32_16x16x32_bf16(pa0, vbr[cf], acc0[cf], 0, 0, 0);
  };

  i32x4 a00, a01, b00, b01;
  f32x4 ea0, ea1, eb0, eb1;
  ldA(0, a00, a01, ea0, ea1);
  ldA(1, b00, b01, eb0, eb1);
  #pragma unroll 1
  for (int s = 0; s < 32; s += 2) {
    step(s, a00, a01, ea0, ea1);
    step(s + 1, b00, b01, eb0, eb1);
  }

  // cross-wave reduction (order-independent additive sums)
  atomicAdd(&denLDS[l16], den0);
  #pragma unroll
  for (int cf = 0; cf < 8; ++cf) {
    #pragma unroll
    for (int r = 0; r < 4; ++r) {
      const int irow = (lk << 2) + r;  // C/D: row=(lane>>4)*4+reg, col=lane&15
      atomicAdd(&numLDS[irow * DD + cf * 16 + l16], acc0[cf][r]);
    }
  }
  __syncthreads();

  // epilogue: divide by denom, ELU, write f32 out (coalesced)
  const int row = t >> 5;          // 0..15
  const int c0 = (t & 31) << 2;    // 0..124
  const float rd = 1.f / denLDS[row];
  f32x4 o;
  #pragma unroll
  for (int q = 0; q < 4; ++q) {
    float v = numLDS[row * DD + c0 + q] * rd;
    o[q] = v > 0.f ? v : (__expf(v) - 1.f);
  }
  *(f32x4*)(out + (size_t)(rowbase + row) * DD + c0) = o;
}

extern "C" void kernel_launch(void* const* d_in, const int* in_sizes, int n_in,
                              void* d_out, int out_size, void* d_ws, size_t ws_size,
                              hipStream_t stream) {
  const float* X = (const float*)d_in[0];
  const int* A = (const int*)d_in[1];
  const float* W = (const float*)d_in[2];
  const float* a_src = (const float*)d_in[3];
  const float* a_dst = (const float*)d_in[4];
  float* out = (float*)d_out;

  char* w = (char*)d_ws;
  float* es = (float*)(w + 0);           // 32 KB
  float* ed = (float*)(w + 32768);       // 32 KB
  bf16_t* Hb = (bf16_t*)(w + 65536);     // 2 MB
  bf16_t* HbT = (bf16_t*)(w + 2162688);  // 2 MB  (total ~4.1 MB)

  hipLaunchKernelGGL(k1_fused, dim3(256), dim3(256), 0, stream, X, W, a_src, a_dst, es,
                     ed, Hb);
  hipLaunchKernelGGL(k1_transpose, dim3(128, 2), dim3(256), 0, stream, Hb, HbT);
  hipLaunchKernelGGL(k2_gat, dim3(512), dim3(512), 0, stream, A, es, ed, HbT, out);
}